// Round 3
// baseline (985.249 us; speedup 1.0000x reference)
//
#include <hip/hip_runtime.h>
#include <hip/hip_bf16.h>
#include <math.h>

// AtnConv (contextual attention) B=2, H=W=64, C=128, k=3.
// R3: FUSED score path — D (X2·X2^T) is never materialized. k_gemm_g computes,
// per block, a 272-row x 80-col skewed band of D via 3-term split-bf16 MFMA
// into LDS (ds[272][66], skewed: ds[r][sc], sc=c-r-S0), then applies the
// 9-tap DIAGONAL stencil (vertical in skewed space, masked at image edges)
// and writes G[x][l] directly. Eliminates 64MB write + 64MB read per batch.
// invn now from exact fp32 pixnorm (k_pixnorm) since D's diagonal is gone.
// Then (unchanged): Ps = pooled logits (skewed) + row softmax stats;
// A2 = diag stencil of softmax(Ps); Y = A2 @ X1 bf16 MFMA split-K.
// ws: buf1 (X2h|X2l -> Ps) 64MB; buf2 (pixn -> G -> A2bf|X1T) 64MB;
// invn/rowm/rowrz at ws+128MB.
// ORDERING: k_invnorm before k_gemm_g (pixn in buf2 head is clobbered by G);
// k_x1t after k_pool_stats (X1T at buf2+32MB overlaps G's tail);
// k_pool_stats writes Ps over X2h/X2l (dead after k_gemm_g).

constexpr int Hh = 64;
constexpr int Ww = 64;
constexpr int CDIM = 128;
constexpr int LDIM = Hh * Ww;   // 4096

typedef __attribute__((ext_vector_type(8))) short bf16x8;
typedef __attribute__((ext_vector_type(4))) float f32x4;
typedef __attribute__((ext_vector_type(2))) float f32x2;

// --------------------------------------------- split X2 into bf16 hi/lo parts
__global__ __launch_bounds__(256)
void k_split(const float* __restrict__ X, __hip_bfloat16* __restrict__ Xh,
             __hip_bfloat16* __restrict__ Xl) {
    const int i = (blockIdx.x * 256 + threadIdx.x) * 4;
    const float4 v = *(const float4*)(X + i);
    __hip_bfloat16 h[4], l[4];
    const float f[4] = {v.x, v.y, v.z, v.w};
    #pragma unroll
    for (int j = 0; j < 4; ++j) {
        h[j] = __float2bfloat16(f[j]);
        l[j] = __float2bfloat16(f[j] - __bfloat162float(h[j]));
    }
    *(ushort4*)(Xh + i) = *(ushort4*)h;
    *(ushort4*)(Xl + i) = *(ushort4*)l;
}

// ------------- pixn[p] = sum_c X2[p][c]^2 (exact fp32). 64 rows per block.
__global__ __launch_bounds__(256)
void k_pixnorm(const float* __restrict__ X2, float* __restrict__ pixn) {
    const int t = threadIdx.x;
    const int row = blockIdx.x * 64 + (t >> 2);
    const int seg = t & 3;
    const float* p = X2 + (size_t)row * CDIM + seg * 32;
    float s = 0.f;
    #pragma unroll
    for (int j = 0; j < 8; ++j) {
        const float4 v = *(const float4*)(p + 4 * j);
        s += v.x * v.x + v.y * v.y + v.z * v.z + v.w * v.w;
    }
    s += __shfl_xor(s, 1);
    s += __shfl_xor(s, 2);
    if (seg == 0) pixn[row] = s;
}

// ---------------- invn[l] = 1/max(sqrt(sum 9-neigh pixn),eps)
__global__ void k_invnorm(const float* __restrict__ pixn, float* __restrict__ invn) {
    const int l = blockIdx.x * 256 + threadIdx.x;
    const int ly = l >> 6, lx = l & 63;
    float s = 0.f;
    #pragma unroll
    for (int ty = -1; ty <= 1; ++ty)
        #pragma unroll
        for (int tx = -1; tx <= 1; ++tx) {
            if ((unsigned)(ly + ty) < 64u && (unsigned)(lx + tx) < 64u)
                s += pixn[l + ty * Ww + tx];
        }
    invn[l] = 1.0f / fmaxf(sqrtf(s), 1e-4f);
}

// -------- FUSED: G[x][l] = sum_o mask * D[x+o][l+o], D = X2·X2^T (3-term
// split-bf16 MFMA), o = dy*64+dx over 3x3. In skewed coords (sc = l-x) the
// stencil is vertical: G_s[x][sc] = sum_o mask * Ds[x+o][sc].
// Block: x-band 128 (blockIdx.y), sc-chunk 64 (blockIdx.x).
// Phase A: MFMA 17 r-tiles x 5 c-tiles covering rows [X0-72,X0+200) x
//          sc [0,64), scatter into LDS ds[272][66].
// Phase B: per-thread (1 x-row, 32 sc) 9-tap masked stencil from LDS -> G.
__global__ __launch_bounds__(256)
void k_gemm_g(const __hip_bfloat16* __restrict__ Xh,
              const __hip_bfloat16* __restrict__ Xl, float* __restrict__ G) {
    __shared__ float ds[272][66];
    const int t = threadIdx.x;
    const int wave = t >> 6, lane = t & 63;
    const int quad = lane >> 4, l16 = lane & 15;
    const int S0 = blockIdx.x * 64;
    const int X0 = blockIdx.y * 128;
    const int Rbase = X0 - 72;

    // ---------------- Phase A: 85 MFMA tile-units across 4 waves
    for (int u = wave; u < 85; u += 4) {
        const int rt = u / 5, ct = u % 5;
        const int Rt = Rbase + rt * 16;
        f32x4 acc = {0.f, 0.f, 0.f, 0.f};
        #pragma unroll
        for (int k0 = 0; k0 < CDIM; k0 += 32) {
            const int kq = k0 + quad * 8;
            const int ra = Rt + l16;
            const int rc = min(max(ra, 0), LDIM - 1);          // clamp halo rows
            const bf16x8 ah = *(const bf16x8*)(Xh + (size_t)rc * CDIM + kq);
            const bf16x8 al = *(const bf16x8*)(Xl + (size_t)rc * CDIM + kq);
            const int cb = (Rt + S0 + ct * 16 + l16) & (LDIM - 1);  // wrap cols
            const bf16x8 bh = *(const bf16x8*)(Xh + (size_t)cb * CDIM + kq);
            const bf16x8 bl = *(const bf16x8*)(Xl + (size_t)cb * CDIM + kq);
            acc = __builtin_amdgcn_mfma_f32_16x16x32_bf16(ah, bh, acc, 0, 0, 0);
            acc = __builtin_amdgcn_mfma_f32_16x16x32_bf16(ah, bl, acc, 0, 0, 0);
            acc = __builtin_amdgcn_mfma_f32_16x16x32_bf16(al, bh, acc, 0, 0, 0);
        }
        // scatter fragment to skewed LDS: row16=quad*4+r, col16=l16
        #pragma unroll
        for (int r = 0; r < 4; ++r) {
            const int row16 = quad * 4 + r;
            const int scl = ct * 16 + l16 - row16;     // sc_local = c - r - S0
            if ((unsigned)scl < 64u)
                ds[rt * 16 + row16][scl] = acc[r];
        }
    }
    __syncthreads();

    // ---------------- Phase B: 9-tap vertical stencil in skewed space
    const int xl = t >> 1, sh = t & 1;
    const int x = X0 + xl;
    const int xy = x >> 6, xx = x & 63;
    const int scb = sh * 32;

    // per-cell l-side edge masks as 32-bit masks (bit i = cell i valid)
    unsigned mLyM = 0, mLyP = 0, mLxM = 0, mLxP = 0;
    #pragma unroll
    for (int i = 0; i < 32; ++i) {
        const int l = (x + S0 + scb + i) & (LDIM - 1);
        const int ly = l >> 6, lx = l & 63;
        if (ly > 0)  mLyM |= 1u << i;
        if (ly < 63) mLyP |= 1u << i;
        if (lx > 0)  mLxM |= 1u << i;
        if (lx < 63) mLxP |= 1u << i;
    }

    f32x2 a[16];
    #pragma unroll
    for (int j = 0; j < 16; ++j) a[j] = (f32x2){0.f, 0.f};

    #pragma unroll
    for (int dy = -1; dy <= 1; ++dy) {
        if ((unsigned)(xy + dy) >= 64u) continue;
        #pragma unroll
        for (int dx = -1; dx <= 1; ++dx) {
            if (dx == -1 && xx == 0) continue;
            if (dx == 1 && xx == 63) continue;
            const unsigned My = (dy < 0) ? mLyM : (dy > 0) ? mLyP : 0xFFFFFFFFu;
            const unsigned Mx = (dx < 0) ? mLxM : (dx > 0) ? mLxP : 0xFFFFFFFFu;
            const unsigned M = My & Mx;
            const int rl = xl + 72 + dy * 64 + dx;     // in [7, 264]
            #pragma unroll
            for (int j = 0; j < 16; ++j) {
                const f32x2 v = *(const f32x2*)&ds[rl][scb + 2 * j];
                if (M & (1u << (2 * j)))     a[j].x += v.x;
                if (M & (1u << (2 * j + 1))) a[j].y += v.y;
            }
        }
    }

    // store 32 G values: G[x][(x+S0+scb+i)&4095], 8 groups of 4
    float* gbase = G + (size_t)x * LDIM;
    const int l0 = (x + S0 + scb) & (LDIM - 1);
    #pragma unroll
    for (int g = 0; g < 8; ++g) {
        const int lg = (l0 + 4 * g) & (LDIM - 1);
        const float v0 = a[2 * g].x, v1 = a[2 * g].y;
        const float v2 = a[2 * g + 1].x, v3 = a[2 * g + 1].y;
        if (lg <= LDIM - 4) {
            if (!(lg & 1)) {
                *(float2*)(gbase + lg)     = make_float2(v0, v1);
                *(float2*)(gbase + lg + 2) = make_float2(v2, v3);
            } else {
                gbase[lg] = v0;
                *(float2*)(gbase + lg + 1) = make_float2(v1, v2);
                gbase[lg + 3] = v3;
            }
        } else {
            gbase[lg] = v0;
            gbase[(lg + 1) & (LDIM - 1)] = v1;
            gbase[(lg + 2) & (LDIM - 1)] = v2;
            gbase[(lg + 3) & (LDIM - 1)] = v3;
        }
    }
}

// ------- P[x,l] = (90/cnt)*invn[l]*sum_s G[x+s,l]; 4-col float4 vectorized.
// Output stored SKEWED row-major: Ps[x][(l-x)&4095] = P[x][l]. Row softmax stats.
__global__ __launch_bounds__(256)
void k_pool_stats(const float* __restrict__ G, const float* __restrict__ invn,
                  float* __restrict__ Ps, float* __restrict__ rowm,
                  float* __restrict__ rowrz) {
    constexpr int T = 8;
    const int x0 = blockIdx.x * T;
    const int t  = threadIdx.x;
    const int xyc = x0 >> 6;
    const int xxb = x0 & 63;
    const int cy = 1 + (xyc > 0) + (xyc < 63);
    float sc[T];
    #pragma unroll
    for (int i = 0; i < T; ++i) {
        const int xx = xxb + i;
        sc[i] = 90.0f / (float)(cy * (1 + (xx > 0) + (xx < 63)));
    }
    float m[T], Z[T];
    #pragma unroll
    for (int i = 0; i < T; ++i) { m[i] = -1e30f; Z[i] = 0.f; }

    for (int ch = 0; ch < 4; ++ch) {
        const int l0 = ch * 1024 + t * 4;
        const f32x4 inl = *(const f32x4*)(invn + l0);
        f32x4 acc[T];
        #pragma unroll
        for (int i = 0; i < T; ++i) acc[i] = (f32x4){0.f, 0.f, 0.f, 0.f};
        #pragma unroll
        for (int c = 0; c < 3; ++c) {
            const int bc = c * 64 - 65;
            const int ty = c - 1;
            if ((unsigned)(xyc + ty) >= 64u) continue;
            f32x4 w[T + 2];
            #pragma unroll
            for (int u = 0; u < T + 2; ++u) {
                const int r = x0 + bc + u;
                w[u] = ((unsigned)r < (unsigned)LDIM)
                         ? *(const f32x4*)(G + (size_t)r * LDIM + l0)
                         : (f32x4){0.f, 0.f, 0.f, 0.f};
            }
            #pragma unroll
            for (int i = 0; i < T; ++i) {
                const int xx = xxb + i;
                if (xx > 0)  acc[i] += w[i];
                acc[i] += w[i + 1];
                if (xx < 63) acc[i] += w[i + 2];
            }
        }
        #pragma unroll
        for (int i = 0; i < T; ++i) {
            const f32x4 p = acc[i] * sc[i] * inl;
            const int x = x0 + i;
            const int c0 = (l0 - x) & (LDIM - 1);
            float* base = Ps + (size_t)x * LDIM;
            if (c0 <= LDIM - 4) {
                if (!(c0 & 1)) {
                    *(float2*)(base + c0)     = make_float2(p.x, p.y);
                    *(float2*)(base + c0 + 2) = make_float2(p.z, p.w);
                } else {
                    base[c0] = p.x;
                    *(float2*)(base + c0 + 1) = make_float2(p.y, p.z);
                    base[c0 + 3] = p.w;
                }
            } else {
                base[c0] = p.x;
                base[(c0 + 1) & (LDIM - 1)] = p.y;
                base[(c0 + 2) & (LDIM - 1)] = p.z;
                base[(c0 + 3) & (LDIM - 1)] = p.w;
            }
            const float mx4 = fmaxf(fmaxf(p.x, p.y), fmaxf(p.z, p.w));
            const float nm = fmaxf(m[i], mx4);
            Z[i] = Z[i] * __expf(m[i] - nm)
                 + __expf(p.x - nm) + __expf(p.y - nm)
                 + __expf(p.z - nm) + __expf(p.w - nm);
            m[i] = nm;
        }
    }
    __shared__ float sm[256], sz[256];
    for (int i = 0; i < T; ++i) {
        __syncthreads();
        sm[t] = m[i]; sz[t] = Z[i];
        __syncthreads();
        for (int off = 128; off > 0; off >>= 1) {
            if (t < off) {
                const float m2 = sm[t + off], z2 = sz[t + off];
                const float nm = fmaxf(sm[t], m2);
                sz[t] = sz[t] * __expf(sm[t] - nm) + z2 * __expf(m2 - nm);
                sm[t] = nm;
            }
            __syncthreads();
        }
        if (t == 0) { rowm[x0 + i] = sm[0]; rowrz[x0 + i] = 1.0f / sz[0]; }
    }
}

// ---- X1 [4096][128] fp32 -> X1T [128][4096] bf16 (LDS-tiled transpose)
// Launched AFTER k_pool_stats: X1T region overlaps G's tail in buf2.
__global__ __launch_bounds__(256)
void k_x1t(const float* __restrict__ X1, __hip_bfloat16* __restrict__ X1T) {
    __shared__ float tile[32][132];
    const int k0 = blockIdx.x * 32;
    const int t  = threadIdx.x;
    const int kr = t >> 3;
    const int c0 = (t & 7) * 16;
    #pragma unroll
    for (int j = 0; j < 4; ++j) {
        const float4 v = *(const float4*)(X1 + (size_t)(k0 + kr) * CDIM + c0 + 4 * j);
        tile[kr][c0 + 4 * j + 0] = v.x;
        tile[kr][c0 + 4 * j + 1] = v.y;
        tile[kr][c0 + 4 * j + 2] = v.z;
        tile[kr][c0 + 4 * j + 3] = v.w;
    }
    __syncthreads();
    const int c  = t >> 1;
    const int kh = (t & 1) * 16;
    __hip_bfloat16 outv[16];
    #pragma unroll
    for (int j = 0; j < 16; ++j)
        outv[j] = __float2bfloat16(tile[kh + j][c]);
    *(ushort4*)(X1T + (size_t)c * LDIM + k0 + kh)      = *(ushort4*)(outv);
    *(ushort4*)(X1T + (size_t)c * LDIM + k0 + kh + 4)  = *(ushort4*)(outv + 4);
    *(ushort4*)(X1T + (size_t)c * LDIM + k0 + kh + 8)  = *(ushort4*)(outv + 8);
    *(ushort4*)(X1T + (size_t)c * LDIM + k0 + kh + 12) = *(ushort4*)(outv + 12);
}

// ---- A2[p,q] = sum_t exp(P[p+t,q+t]-m)*rz. Reads skewed Ps vertically.
__global__ __launch_bounds__(256)
void k_att2(const float* __restrict__ Ps, const float* __restrict__ rowm,
            const float* __restrict__ rowrz, __hip_bfloat16* __restrict__ A2) {
    constexpr int T = 8;
    const int d0 = (blockIdx.x * 256 + threadIdx.x) * 4;
    const int p0 = blockIdx.y * T;
    const int pyc = p0 >> 6;
    const int pxb = p0 & 63;
    float acc[T][4] = {};
    #pragma unroll
    for (int c = 0; c < 3; ++c) {
        const int bc = c * 64 - 65;          // -65, -1, 63
        const int ty = c - 1;
        if ((unsigned)(pyc + ty) >= 64u) continue;
        float e[T + 2][4];
        #pragma unroll
        for (int u = 0; u < T + 2; ++u) {
            const int r = p0 + bc + u;
            if ((unsigned)r < (unsigned)LDIM) {
                const f32x4 w = *(const f32x4*)(Ps + (size_t)r * LDIM + d0);
                const float mr = rowm[r], rzr = rowrz[r];
                e[u][0] = __expf(w.x - mr) * rzr;
                e[u][1] = __expf(w.y - mr) * rzr;
                e[u][2] = __expf(w.z - mr) * rzr;
                e[u][3] = __expf(w.w - mr) * rzr;
            } else {
                e[u][0] = e[u][1] = e[u][2] = e[u][3] = 0.f;
            }
        }
        #pragma unroll
        for (int i = 0; i < T; ++i) {
            const int px = pxb + i;
            const int p  = p0 + i;
            #pragma unroll
            for (int j = 0; j < 4; ++j) {
                const int q  = (p + d0 + j) & (LDIM - 1);
                const int qy = q >> 6, qx = q & 63;
                if ((unsigned)(qy + ty) < 64u) {
                    float s = acc[i][j];
                    if (px > 0 && qx > 0)   s += e[i][j];
                    s += e[i + 1][j];
                    if (px < 63 && qx < 63) s += e[i + 2][j];
                    acc[i][j] = s;
                }
            }
        }
    }
    #pragma unroll
    for (int i = 0; i < T; ++i) {
        const int p = p0 + i;
        const int q0i = (p + d0) & (LDIM - 1);
        union { __hip_bfloat16 h[4]; unsigned short us[4]; unsigned int ui[2]; } cv;
        #pragma unroll
        for (int j = 0; j < 4; ++j) cv.h[j] = __float2bfloat16(acc[i][j]);
        unsigned short* bp = (unsigned short*)(A2 + (size_t)p * LDIM);
        if (q0i <= LDIM - 4) {
            if (!(q0i & 1)) {
                *(unsigned int*)(bp + q0i)     = cv.ui[0];
                *(unsigned int*)(bp + q0i + 2) = cv.ui[1];
            } else {
                bp[q0i] = cv.us[0];
                *(unsigned int*)(bp + q0i + 1) =
                    (unsigned int)cv.us[1] | ((unsigned int)cv.us[2] << 16);
                bp[q0i + 3] = cv.us[3];
            }
        } else {
            #pragma unroll
            for (int j = 0; j < 4; ++j)
                bp[(q0i + j) & (LDIM - 1)] = cv.us[j];
        }
    }
}

// ---------------- Y += A2 @ X1 (bf16 MFMA, split-K=8, atomic f32 epilogue)
__global__ __launch_bounds__(256)
void k_gemm_y(const __hip_bfloat16* __restrict__ A2b,
              const __hip_bfloat16* __restrict__ X1T, float* __restrict__ Y) {
    const int t = threadIdx.x;
    const int wave = t >> 6, lane = t & 63;
    const int quad = lane >> 4, l16 = lane & 15;
    const int bm = blockIdx.x * 128 + wave * 32;
    const int kc = blockIdx.y * 512;
    f32x4 acc[2][8] = {};
    for (int ks = 0; ks < 512; ks += 32) {
        const int kq = kc + ks + quad * 8;
        bf16x8 a[2], b[8];
        #pragma unroll
        for (int mi = 0; mi < 2; ++mi)
            a[mi] = *(const bf16x8*)(A2b + (size_t)(bm + mi * 16 + l16) * LDIM + kq);
        #pragma unroll
        for (int nf = 0; nf < 8; ++nf)
            b[nf] = *(const bf16x8*)(X1T + (size_t)(nf * 16 + l16) * LDIM + kq);
        #pragma unroll
        for (int mi = 0; mi < 2; ++mi)
            #pragma unroll
            for (int nf = 0; nf < 8; ++nf)
                acc[mi][nf] = __builtin_amdgcn_mfma_f32_16x16x32_bf16(a[mi], b[nf], acc[mi][nf], 0, 0, 0);
    }
    #pragma unroll
    for (int mi = 0; mi < 2; ++mi)
        #pragma unroll
        for (int nf = 0; nf < 8; ++nf)
            #pragma unroll
            for (int r = 0; r < 4; ++r)
                atomicAdd(Y + (size_t)(bm + mi * 16 + quad * 4 + r) * CDIM + nf * 16 + l16,
                          acc[mi][nf][r]);
}

extern "C" void kernel_launch(void* const* d_in, const int* in_sizes, int n_in,
                              void* d_out, int out_size, void* d_ws, size_t ws_size,
                              hipStream_t stream) {
    const float* x1 = (const float*)d_in[0];
    const float* x2 = (const float*)d_in[1];
    float* out = (float*)d_out;

    const size_t MATB = (size_t)LDIM * LDIM * sizeof(float);   // 64 MB
    char* ws = (char*)d_ws;
    float* buf1  = (float*)ws;                         // X2h|X2l, then Ps (fp32)
    char*  buf2c = ws + MATB;                          // multi-use 64 MB
    float* buf2  = (float*)buf2c;                      // pixn, then G (fp32)
    __hip_bfloat16* X2h = (__hip_bfloat16*)ws;                       // 1 MB
    __hip_bfloat16* X2l = (__hip_bfloat16*)(ws + (size_t)LDIM * CDIM * 2);
    float* pixn = (float*)buf2c;                                     // 16 KB
    __hip_bfloat16* A2b = (__hip_bfloat16*)buf2c;                    // 32 MB
    __hip_bfloat16* X1T = (__hip_bfloat16*)(buf2c + MATB / 2);       // 1 MB
    float* invn  = (float*)(ws + 2 * MATB);
    float* rowm  = invn + LDIM;
    float* rowrz = rowm + LDIM;

    const int B = in_sizes[0] / (LDIM * CDIM);

    hipMemsetAsync(d_out, 0, (size_t)out_size * sizeof(float), stream);

    for (int b = 0; b < B; ++b) {
        const float* X2b_ = x2 + (size_t)b * LDIM * CDIM;
        const float* X1b_ = x1 + (size_t)b * LDIM * CDIM;
        float* Yb = out + (size_t)b * LDIM * CDIM;

        k_split     <<<LDIM * CDIM / 1024, 256, 0, stream>>>(X2b_, X2h, X2l);
        k_pixnorm   <<<LDIM / 64, 256, 0, stream>>>(X2b_, pixn);
        k_invnorm   <<<LDIM / 256, 256, 0, stream>>>(pixn, invn);
        k_gemm_g    <<<dim3(LDIM / 64, LDIM / 128), 256, 0, stream>>>(X2h, X2l, buf2);
        k_pool_stats<<<LDIM / 8, 256, 0, stream>>>(buf2, invn, buf1, rowm, rowrz);
        k_x1t       <<<LDIM / 32, 256, 0, stream>>>(X1b_, X1T);
        k_att2      <<<dim3(LDIM / 1024, LDIM / 8), 256, 0, stream>>>(buf1, rowm, rowrz, A2b);
        k_gemm_y    <<<dim3(LDIM / 128, 8), 256, 0, stream>>>(A2b, X1T, Yb);
    }
}

// Round 4
// 761.183 us; speedup vs baseline: 1.2944x; 1.2944x over previous
//
#include <hip/hip_runtime.h>
#include <hip/hip_bf16.h>
#include <math.h>

// AtnConv (contextual attention) B=2, H=W=64, C=128, k=3.
// R4: FUSED score path, register-blocked. D (X2·X2^T) never hits HBM.
// k_gemm_g per block: 272-row x 80-col skewed band of D via 3-term split-bf16
// MFMA into LDS ds[272][66] (skewed: ds[r][sc], sc=c-r-S0), then 9-tap
// DIAGONAL stencil (vertical in skewed space, masked at image edges) -> G.
// R4 change vs R3: Phase A waves own whole r-tiles (5 c-tile accumulators,
// A-fragments loaded once per K-step, col addresses hoisted) -> 15 independent
// MFMAs per 12 loads instead of 3 chained MFMAs per 4 loads. Phase B and all
// masks identical to R3 (which PASSED; it was only slow).
// invn from exact fp32 pixnorm. Then (unchanged): Ps = pooled logits (skewed)
// + row softmax stats; A2 = diag stencil of softmax(Ps); Y = A2 @ X1 MFMA.
// ws: buf1 (X2h|X2l -> Ps) 64MB; buf2 (pixn -> G -> A2bf|X1T) 64MB;
// invn/rowm/rowrz at ws+128MB.
// ORDERING: k_invnorm before k_gemm_g (pixn in buf2 head clobbered by G);
// k_x1t after k_pool_stats (X1T at buf2+32MB overlaps G's tail);
// k_pool_stats writes Ps over X2h/X2l (dead after k_gemm_g).

constexpr int Hh = 64;
constexpr int Ww = 64;
constexpr int CDIM = 128;
constexpr int LDIM = Hh * Ww;   // 4096

typedef __attribute__((ext_vector_type(8))) short bf16x8;
typedef __attribute__((ext_vector_type(4))) float f32x4;
typedef __attribute__((ext_vector_type(2))) float f32x2;

// --------------------------------------------- split X2 into bf16 hi/lo parts
__global__ __launch_bounds__(256)
void k_split(const float* __restrict__ X, __hip_bfloat16* __restrict__ Xh,
             __hip_bfloat16* __restrict__ Xl) {
    const int i = (blockIdx.x * 256 + threadIdx.x) * 4;
    const float4 v = *(const float4*)(X + i);
    __hip_bfloat16 h[4], l[4];
    const float f[4] = {v.x, v.y, v.z, v.w};
    #pragma unroll
    for (int j = 0; j < 4; ++j) {
        h[j] = __float2bfloat16(f[j]);
        l[j] = __float2bfloat16(f[j] - __bfloat162float(h[j]));
    }
    *(ushort4*)(Xh + i) = *(ushort4*)h;
    *(ushort4*)(Xl + i) = *(ushort4*)l;
}

// ------------- pixn[p] = sum_c X2[p][c]^2 (exact fp32). 64 rows per block.
__global__ __launch_bounds__(256)
void k_pixnorm(const float* __restrict__ X2, float* __restrict__ pixn) {
    const int t = threadIdx.x;
    const int row = blockIdx.x * 64 + (t >> 2);
    const int seg = t & 3;
    const float* p = X2 + (size_t)row * CDIM + seg * 32;
    float s = 0.f;
    #pragma unroll
    for (int j = 0; j < 8; ++j) {
        const float4 v = *(const float4*)(p + 4 * j);
        s += v.x * v.x + v.y * v.y + v.z * v.z + v.w * v.w;
    }
    s += __shfl_xor(s, 1);
    s += __shfl_xor(s, 2);
    if (seg == 0) pixn[row] = s;
}

// ---------------- invn[l] = 1/max(sqrt(sum 9-neigh pixn),eps)
__global__ void k_invnorm(const float* __restrict__ pixn, float* __restrict__ invn) {
    const int l = blockIdx.x * 256 + threadIdx.x;
    const int ly = l >> 6, lx = l & 63;
    float s = 0.f;
    #pragma unroll
    for (int ty = -1; ty <= 1; ++ty)
        #pragma unroll
        for (int tx = -1; tx <= 1; ++tx) {
            if ((unsigned)(ly + ty) < 64u && (unsigned)(lx + tx) < 64u)
                s += pixn[l + ty * Ww + tx];
        }
    invn[l] = 1.0f / fmaxf(sqrtf(s), 1e-4f);
}

// -------- FUSED: G[x][l] = sum_o mask * D[x+o][l+o], D = X2·X2^T (3-term
// split-bf16 MFMA), o = dy*64+dx over 3x3. In skewed coords (sc = l-x) the
// stencil is vertical: G_s[x][sc] = sum_o mask * Ds[x+o][sc].
// Block: x-band 128 (blockIdx.y), sc-chunk 64 (blockIdx.x).
// Phase A: 17 r-tiles x 5 c-tiles covering rows [X0-72,X0+200) x sc [0,64);
//          each wave owns whole r-tiles (reg-blocked, 5 accs), scatter to LDS.
// Phase B: per-thread (1 x-row, 32 sc) 9-tap masked stencil from LDS -> G.
__global__ __launch_bounds__(256)
void k_gemm_g(const __hip_bfloat16* __restrict__ Xh,
              const __hip_bfloat16* __restrict__ Xl, float* __restrict__ G) {
    __shared__ float ds[272][66];
    const int t = threadIdx.x;
    const int wave = t >> 6, lane = t & 63;
    const int quad = lane >> 4, l16 = lane & 15;
    const int S0 = blockIdx.x * 64;
    const int X0 = blockIdx.y * 128;
    const int Rbase = X0 - 72;

    // ---------------- Phase A: register-blocked band GEMM
    for (int rt = wave; rt < 17; rt += 4) {
        const int Rt = Rbase + rt * 16;
        const int ra = Rt + l16;
        const int rc = min(max(ra, 0), LDIM - 1);          // clamp halo rows
        const __hip_bfloat16* arh = Xh + (size_t)rc * CDIM;
        const __hip_bfloat16* arl = Xl + (size_t)rc * CDIM;
        size_t cro[5];
        #pragma unroll
        for (int ct = 0; ct < 5; ++ct)
            cro[ct] = (size_t)((Rt + S0 + ct * 16 + l16) & (LDIM - 1)) * CDIM;
        f32x4 acc[5] = {};
        #pragma unroll
        for (int k0 = 0; k0 < CDIM; k0 += 32) {
            const int kq = k0 + quad * 8;
            const bf16x8 ah = *(const bf16x8*)(arh + kq);
            const bf16x8 al = *(const bf16x8*)(arl + kq);
            bf16x8 bh[5], bl[5];
            #pragma unroll
            for (int ct = 0; ct < 5; ++ct) {
                bh[ct] = *(const bf16x8*)(Xh + cro[ct] + kq);
                bl[ct] = *(const bf16x8*)(Xl + cro[ct] + kq);
            }
            #pragma unroll
            for (int ct = 0; ct < 5; ++ct) {
                acc[ct] = __builtin_amdgcn_mfma_f32_16x16x32_bf16(ah, bh[ct], acc[ct], 0, 0, 0);
                acc[ct] = __builtin_amdgcn_mfma_f32_16x16x32_bf16(ah, bl[ct], acc[ct], 0, 0, 0);
                acc[ct] = __builtin_amdgcn_mfma_f32_16x16x32_bf16(al, bh[ct], acc[ct], 0, 0, 0);
            }
        }
        // scatter fragments to skewed LDS: row16=quad*4+r, col16=l16
        #pragma unroll
        for (int ct = 0; ct < 5; ++ct)
            #pragma unroll
            for (int r = 0; r < 4; ++r) {
                const int row16 = quad * 4 + r;
                const int scl = ct * 16 + l16 - row16;     // sc_local
                if ((unsigned)scl < 64u)
                    ds[rt * 16 + row16][scl] = acc[ct][r];
            }
    }
    __syncthreads();

    // ---------------- Phase B: 9-tap vertical stencil in skewed space
    const int xl = t >> 1, sh = t & 1;
    const int x = X0 + xl;
    const int xy = x >> 6, xx = x & 63;
    const int scb = sh * 32;

    // per-cell l-side edge masks as 32-bit masks (bit i = cell i valid)
    unsigned mLyM = 0, mLyP = 0, mLxM = 0, mLxP = 0;
    #pragma unroll
    for (int i = 0; i < 32; ++i) {
        const int l = (x + S0 + scb + i) & (LDIM - 1);
        const int ly = l >> 6, lx = l & 63;
        if (ly > 0)  mLyM |= 1u << i;
        if (ly < 63) mLyP |= 1u << i;
        if (lx > 0)  mLxM |= 1u << i;
        if (lx < 63) mLxP |= 1u << i;
    }

    f32x2 a[16];
    #pragma unroll
    for (int j = 0; j < 16; ++j) a[j] = (f32x2){0.f, 0.f};

    #pragma unroll
    for (int dy = -1; dy <= 1; ++dy) {
        if ((unsigned)(xy + dy) >= 64u) continue;
        #pragma unroll
        for (int dx = -1; dx <= 1; ++dx) {
            if (dx == -1 && xx == 0) continue;
            if (dx == 1 && xx == 63) continue;
            const unsigned My = (dy < 0) ? mLyM : (dy > 0) ? mLyP : 0xFFFFFFFFu;
            const unsigned Mx = (dx < 0) ? mLxM : (dx > 0) ? mLxP : 0xFFFFFFFFu;
            const unsigned M = My & Mx;
            const int rl = xl + 72 + dy * 64 + dx;     // in [7, 264]
            #pragma unroll
            for (int j = 0; j < 16; ++j) {
                const f32x2 v = *(const f32x2*)&ds[rl][scb + 2 * j];
                if (M & (1u << (2 * j)))     a[j].x += v.x;
                if (M & (1u << (2 * j + 1))) a[j].y += v.y;
            }
        }
    }

    // store 32 G values: G[x][(x+S0+scb+i)&4095], 8 groups of 4
    float* gbase = G + (size_t)x * LDIM;
    const int l0 = (x + S0 + scb) & (LDIM - 1);
    #pragma unroll
    for (int g = 0; g < 8; ++g) {
        const int lg = (l0 + 4 * g) & (LDIM - 1);
        const float v0 = a[2 * g].x, v1 = a[2 * g].y;
        const float v2 = a[2 * g + 1].x, v3 = a[2 * g + 1].y;
        if (lg <= LDIM - 4) {
            if (!(lg & 1)) {
                *(float2*)(gbase + lg)     = make_float2(v0, v1);
                *(float2*)(gbase + lg + 2) = make_float2(v2, v3);
            } else {
                gbase[lg] = v0;
                *(float2*)(gbase + lg + 1) = make_float2(v1, v2);
                gbase[lg + 3] = v3;
            }
        } else {
            gbase[lg] = v0;
            gbase[(lg + 1) & (LDIM - 1)] = v1;
            gbase[(lg + 2) & (LDIM - 1)] = v2;
            gbase[(lg + 3) & (LDIM - 1)] = v3;
        }
    }
}

// ------- P[x,l] = (90/cnt)*invn[l]*sum_s G[x+s,l]; 4-col float4 vectorized.
// Output stored SKEWED row-major: Ps[x][(l-x)&4095] = P[x][l]. Row softmax stats.
__global__ __launch_bounds__(256)
void k_pool_stats(const float* __restrict__ G, const float* __restrict__ invn,
                  float* __restrict__ Ps, float* __restrict__ rowm,
                  float* __restrict__ rowrz) {
    constexpr int T = 8;
    const int x0 = blockIdx.x * T;
    const int t  = threadIdx.x;
    const int xyc = x0 >> 6;
    const int xxb = x0 & 63;
    const int cy = 1 + (xyc > 0) + (xyc < 63);
    float sc[T];
    #pragma unroll
    for (int i = 0; i < T; ++i) {
        const int xx = xxb + i;
        sc[i] = 90.0f / (float)(cy * (1 + (xx > 0) + (xx < 63)));
    }
    float m[T], Z[T];
    #pragma unroll
    for (int i = 0; i < T; ++i) { m[i] = -1e30f; Z[i] = 0.f; }

    for (int ch = 0; ch < 4; ++ch) {
        const int l0 = ch * 1024 + t * 4;
        const f32x4 inl = *(const f32x4*)(invn + l0);
        f32x4 acc[T];
        #pragma unroll
        for (int i = 0; i < T; ++i) acc[i] = (f32x4){0.f, 0.f, 0.f, 0.f};
        #pragma unroll
        for (int c = 0; c < 3; ++c) {
            const int bc = c * 64 - 65;
            const int ty = c - 1;
            if ((unsigned)(xyc + ty) >= 64u) continue;
            f32x4 w[T + 2];
            #pragma unroll
            for (int u = 0; u < T + 2; ++u) {
                const int r = x0 + bc + u;
                w[u] = ((unsigned)r < (unsigned)LDIM)
                         ? *(const f32x4*)(G + (size_t)r * LDIM + l0)
                         : (f32x4){0.f, 0.f, 0.f, 0.f};
            }
            #pragma unroll
            for (int i = 0; i < T; ++i) {
                const int xx = xxb + i;
                if (xx > 0)  acc[i] += w[i];
                acc[i] += w[i + 1];
                if (xx < 63) acc[i] += w[i + 2];
            }
        }
        #pragma unroll
        for (int i = 0; i < T; ++i) {
            const f32x4 p = acc[i] * sc[i] * inl;
            const int x = x0 + i;
            const int c0 = (l0 - x) & (LDIM - 1);
            float* base = Ps + (size_t)x * LDIM;
            if (c0 <= LDIM - 4) {
                if (!(c0 & 1)) {
                    *(float2*)(base + c0)     = make_float2(p.x, p.y);
                    *(float2*)(base + c0 + 2) = make_float2(p.z, p.w);
                } else {
                    base[c0] = p.x;
                    *(float2*)(base + c0 + 1) = make_float2(p.y, p.z);
                    base[c0 + 3] = p.w;
                }
            } else {
                base[c0] = p.x;
                base[(c0 + 1) & (LDIM - 1)] = p.y;
                base[(c0 + 2) & (LDIM - 1)] = p.z;
                base[(c0 + 3) & (LDIM - 1)] = p.w;
            }
            const float mx4 = fmaxf(fmaxf(p.x, p.y), fmaxf(p.z, p.w));
            const float nm = fmaxf(m[i], mx4);
            Z[i] = Z[i] * __expf(m[i] - nm)
                 + __expf(p.x - nm) + __expf(p.y - nm)
                 + __expf(p.z - nm) + __expf(p.w - nm);
            m[i] = nm;
        }
    }
    __shared__ float sm[256], sz[256];
    for (int i = 0; i < T; ++i) {
        __syncthreads();
        sm[t] = m[i]; sz[t] = Z[i];
        __syncthreads();
        for (int off = 128; off > 0; off >>= 1) {
            if (t < off) {
                const float m2 = sm[t + off], z2 = sz[t + off];
                const float nm = fmaxf(sm[t], m2);
                sz[t] = sz[t] * __expf(sm[t] - nm) + z2 * __expf(m2 - nm);
                sm[t] = nm;
            }
            __syncthreads();
        }
        if (t == 0) { rowm[x0 + i] = sm[0]; rowrz[x0 + i] = 1.0f / sz[0]; }
    }
}

// ---- X1 [4096][128] fp32 -> X1T [128][4096] bf16 (LDS-tiled transpose)
// Launched AFTER k_pool_stats: X1T region overlaps G's tail in buf2.
__global__ __launch_bounds__(256)
void k_x1t(const float* __restrict__ X1, __hip_bfloat16* __restrict__ X1T) {
    __shared__ float tile[32][132];
    const int k0 = blockIdx.x * 32;
    const int t  = threadIdx.x;
    const int kr = t >> 3;
    const int c0 = (t & 7) * 16;
    #pragma unroll
    for (int j = 0; j < 4; ++j) {
        const float4 v = *(const float4*)(X1 + (size_t)(k0 + kr) * CDIM + c0 + 4 * j);
        tile[kr][c0 + 4 * j + 0] = v.x;
        tile[kr][c0 + 4 * j + 1] = v.y;
        tile[kr][c0 + 4 * j + 2] = v.z;
        tile[kr][c0 + 4 * j + 3] = v.w;
    }
    __syncthreads();
    const int c  = t >> 1;
    const int kh = (t & 1) * 16;
    __hip_bfloat16 outv[16];
    #pragma unroll
    for (int j = 0; j < 16; ++j)
        outv[j] = __float2bfloat16(tile[kh + j][c]);
    *(ushort4*)(X1T + (size_t)c * LDIM + k0 + kh)      = *(ushort4*)(outv);
    *(ushort4*)(X1T + (size_t)c * LDIM + k0 + kh + 4)  = *(ushort4*)(outv + 4);
    *(ushort4*)(X1T + (size_t)c * LDIM + k0 + kh + 8)  = *(ushort4*)(outv + 8);
    *(ushort4*)(X1T + (size_t)c * LDIM + k0 + kh + 12) = *(ushort4*)(outv + 12);
}

// ---- A2[p,q] = sum_t exp(P[p+t,q+t]-m)*rz. Reads skewed Ps vertically.
__global__ __launch_bounds__(256)
void k_att2(const float* __restrict__ Ps, const float* __restrict__ rowm,
            const float* __restrict__ rowrz, __hip_bfloat16* __restrict__ A2) {
    constexpr int T = 8;
    const int d0 = (blockIdx.x * 256 + threadIdx.x) * 4;
    const int p0 = blockIdx.y * T;
    const int pyc = p0 >> 6;
    const int pxb = p0 & 63;
    float acc[T][4] = {};
    #pragma unroll
    for (int c = 0; c < 3; ++c) {
        const int bc = c * 64 - 65;          // -65, -1, 63
        const int ty = c - 1;
        if ((unsigned)(pyc + ty) >= 64u) continue;
        float e[T + 2][4];
        #pragma unroll
        for (int u = 0; u < T + 2; ++u) {
            const int r = p0 + bc + u;
            if ((unsigned)r < (unsigned)LDIM) {
                const f32x4 w = *(const f32x4*)(Ps + (size_t)r * LDIM + d0);
                const float mr = rowm[r], rzr = rowrz[r];
                e[u][0] = __expf(w.x - mr) * rzr;
                e[u][1] = __expf(w.y - mr) * rzr;
                e[u][2] = __expf(w.z - mr) * rzr;
                e[u][3] = __expf(w.w - mr) * rzr;
            } else {
                e[u][0] = e[u][1] = e[u][2] = e[u][3] = 0.f;
            }
        }
        #pragma unroll
        for (int i = 0; i < T; ++i) {
            const int px = pxb + i;
            const int p  = p0 + i;
            #pragma unroll
            for (int j = 0; j < 4; ++j) {
                const int q  = (p + d0 + j) & (LDIM - 1);
                const int qy = q >> 6, qx = q & 63;
                if ((unsigned)(qy + ty) < 64u) {
                    float s = acc[i][j];
                    if (px > 0 && qx > 0)   s += e[i][j];
                    s += e[i + 1][j];
                    if (px < 63 && qx < 63) s += e[i + 2][j];
                    acc[i][j] = s;
                }
            }
        }
    }
    #pragma unroll
    for (int i = 0; i < T; ++i) {
        const int p = p0 + i;
        const int q0i = (p + d0) & (LDIM - 1);
        union { __hip_bfloat16 h[4]; unsigned short us[4]; unsigned int ui[2]; } cv;
        #pragma unroll
        for (int j = 0; j < 4; ++j) cv.h[j] = __float2bfloat16(acc[i][j]);
        unsigned short* bp = (unsigned short*)(A2 + (size_t)p * LDIM);
        if (q0i <= LDIM - 4) {
            if (!(q0i & 1)) {
                *(unsigned int*)(bp + q0i)     = cv.ui[0];
                *(unsigned int*)(bp + q0i + 2) = cv.ui[1];
            } else {
                bp[q0i] = cv.us[0];
                *(unsigned int*)(bp + q0i + 1) =
                    (unsigned int)cv.us[1] | ((unsigned int)cv.us[2] << 16);
                bp[q0i + 3] = cv.us[3];
            }
        } else {
            #pragma unroll
            for (int j = 0; j < 4; ++j)
                bp[(q0i + j) & (LDIM - 1)] = cv.us[j];
        }
    }
}

// ---------------- Y += A2 @ X1 (bf16 MFMA, split-K=8, atomic f32 epilogue)
__global__ __launch_bounds__(256)
void k_gemm_y(const __hip_bfloat16* __restrict__ A2b,
              const __hip_bfloat16* __restrict__ X1T, float* __restrict__ Y) {
    const int t = threadIdx.x;
    const int wave = t >> 6, lane = t & 63;
    const int quad = lane >> 4, l16 = lane & 15;
    const int bm = blockIdx.x * 128 + wave * 32;
    const int kc = blockIdx.y * 512;
    f32x4 acc[2][8] = {};
    for (int ks = 0; ks < 512; ks += 32) {
        const int kq = kc + ks + quad * 8;
        bf16x8 a[2], b[8];
        #pragma unroll
        for (int mi = 0; mi < 2; ++mi)
            a[mi] = *(const bf16x8*)(A2b + (size_t)(bm + mi * 16 + l16) * LDIM + kq);
        #pragma unroll
        for (int nf = 0; nf < 8; ++nf)
            b[nf] = *(const bf16x8*)(X1T + (size_t)(nf * 16 + l16) * LDIM + kq);
        #pragma unroll
        for (int mi = 0; mi < 2; ++mi)
            #pragma unroll
            for (int nf = 0; nf < 8; ++nf)
                acc[mi][nf] = __builtin_amdgcn_mfma_f32_16x16x32_bf16(a[mi], b[nf], acc[mi][nf], 0, 0, 0);
    }
    #pragma unroll
    for (int mi = 0; mi < 2; ++mi)
        #pragma unroll
        for (int nf = 0; nf < 8; ++nf)
            #pragma unroll
            for (int r = 0; r < 4; ++r)
                atomicAdd(Y + (size_t)(bm + mi * 16 + quad * 4 + r) * CDIM + nf * 16 + l16,
                          acc[mi][nf][r]);
}

extern "C" void kernel_launch(void* const* d_in, const int* in_sizes, int n_in,
                              void* d_out, int out_size, void* d_ws, size_t ws_size,
                              hipStream_t stream) {
    const float* x1 = (const float*)d_in[0];
    const float* x2 = (const float*)d_in[1];
    float* out = (float*)d_out;

    const size_t MATB = (size_t)LDIM * LDIM * sizeof(float);   // 64 MB
    char* ws = (char*)d_ws;
    float* buf1  = (float*)ws;                         // X2h|X2l, then Ps (fp32)
    char*  buf2c = ws + MATB;                          // multi-use 64 MB
    float* buf2  = (float*)buf2c;                      // pixn, then G (fp32)
    __hip_bfloat16* X2h = (__hip_bfloat16*)ws;                       // 1 MB
    __hip_bfloat16* X2l = (__hip_bfloat16*)(ws + (size_t)LDIM * CDIM * 2);
    float* pixn = (float*)buf2c;                                     // 16 KB
    __hip_bfloat16* A2b = (__hip_bfloat16*)buf2c;                    // 32 MB
    __hip_bfloat16* X1T = (__hip_bfloat16*)(buf2c + MATB / 2);       // 1 MB
    float* invn  = (float*)(ws + 2 * MATB);
    float* rowm  = invn + LDIM;
    float* rowrz = rowm + LDIM;

    const int B = in_sizes[0] / (LDIM * CDIM);

    hipMemsetAsync(d_out, 0, (size_t)out_size * sizeof(float), stream);

    for (int b = 0; b < B; ++b) {
        const float* X2b_ = x2 + (size_t)b * LDIM * CDIM;
        const float* X1b_ = x1 + (size_t)b * LDIM * CDIM;
        float* Yb = out + (size_t)b * LDIM * CDIM;

        k_split     <<<LDIM * CDIM / 1024, 256, 0, stream>>>(X2b_, X2h, X2l);
        k_pixnorm   <<<LDIM / 64, 256, 0, stream>>>(X2b_, pixn);
        k_invnorm   <<<LDIM / 256, 256, 0, stream>>>(pixn, invn);
        k_gemm_g    <<<dim3(LDIM / 64, LDIM / 128), 256, 0, stream>>>(X2h, X2l, buf2);
        k_pool_stats<<<LDIM / 8, 256, 0, stream>>>(buf2, invn, buf1, rowm, rowrz);
        k_x1t       <<<LDIM / 32, 256, 0, stream>>>(X1b_, X1T);
        k_att2      <<<dim3(LDIM / 1024, LDIM / 8), 256, 0, stream>>>(buf1, rowm, rowrz, A2b);
        k_gemm_y    <<<dim3(LDIM / 128, 8), 256, 0, stream>>>(A2b, X1T, Yb);
    }
}

// Round 5
// 482.523 us; speedup vs baseline: 2.0419x; 1.5775x over previous
//
#include <hip/hip_runtime.h>
#include <hip/hip_bf16.h>
#include <math.h>

// AtnConv (contextual attention) B=2, H=W=64, C=128, k=3.
// R5: revert to R0 champion structure (480.75us measured) + batch-concurrent
// grids. All kernels gain blockIdx.z (batch); each batch gets its own ws slice
// so both batches' pipelines run concurrently (doubles occupancy of the
// latency-bound middle kernels, halves launch bubbles). If ws_size is too
// small for 2 slices, falls back to the exact sequential R0 path.
// Score path fp32: Ds = skewed X2·X2^T (split-bf16 MFMA, Ds[r][(c-r)&4095]);
// invn from skewed col 0; G = 9-tap diag stencil read VERTICALLY from Ds;
// Ps = pooled logits (skewed) + row softmax stats. Value path bf16:
// A2 = diag stencil of softmax(Ps); Y = A2 @ X1 bf16 MFMA split-K.
// Per-slice: buf1 (Ds->Ps) 64MB; buf2 (X2h/X2l -> G -> A2bf|X1T) 64MB;
// invn/rowm/rowrz. NOTE: k_x1t after k_pool_stats (X1T overlaps G tail).
// R1/R2 lessons: gemm_d store pattern (coalescing, DRAM tiling) is NOT the
// limiter; R3/R4 lesson: fusing D->G costs more than it saves (LDS-occupancy).

constexpr int Hh = 64;
constexpr int Ww = 64;
constexpr int CDIM = 128;
constexpr int LDIM = Hh * Ww;   // 4096

typedef __attribute__((ext_vector_type(8))) short bf16x8;
typedef __attribute__((ext_vector_type(4))) float f32x4;

// --------------------------------------------- split X2 into bf16 hi/lo parts
__global__ __launch_bounds__(256)
void k_split(const float* __restrict__ X, __hip_bfloat16* __restrict__ Xh_,
             __hip_bfloat16* __restrict__ Xl_, size_t inStrideF, size_t wsStrideB) {
    const int z = blockIdx.z;
    const float* Xb = X + (size_t)z * inStrideF;
    __hip_bfloat16* Xh = (__hip_bfloat16*)((char*)Xh_ + (size_t)z * wsStrideB);
    __hip_bfloat16* Xl = (__hip_bfloat16*)((char*)Xl_ + (size_t)z * wsStrideB);
    const int i = (blockIdx.x * 256 + threadIdx.x) * 4;
    const float4 v = *(const float4*)(Xb + i);
    __hip_bfloat16 h[4], l[4];
    const float f[4] = {v.x, v.y, v.z, v.w};
    #pragma unroll
    for (int j = 0; j < 4; ++j) {
        h[j] = __float2bfloat16(f[j]);
        l[j] = __float2bfloat16(f[j] - __bfloat162float(h[j]));
    }
    *(ushort4*)(Xh + i) = *(ushort4*)h;
    *(ushort4*)(Xl + i) = *(ushort4*)l;
}

// -------- Ds = skewed X2·X2^T via 3-term split-bf16 MFMA; Ds[r][(c-r)&4095]
__global__ __launch_bounds__(256)
void k_gemm_d(const __hip_bfloat16* __restrict__ Xh_,
              const __hip_bfloat16* __restrict__ Xl_, float* __restrict__ Ds_,
              size_t wsStrideB) {
    const int z = blockIdx.z;
    const __hip_bfloat16* Xh = (const __hip_bfloat16*)((const char*)Xh_ + (size_t)z * wsStrideB);
    const __hip_bfloat16* Xl = (const __hip_bfloat16*)((const char*)Xl_ + (size_t)z * wsStrideB);
    float* Ds = (float*)((char*)Ds_ + (size_t)z * wsStrideB);
    const int t = threadIdx.x;
    const int wave = t >> 6, lane = t & 63;
    const int quad = lane >> 4, l16 = lane & 15;
    const int bm = blockIdx.x * 128 + wave * 32;
    const int bn = blockIdx.y * 128;
    f32x4 acc[2][8] = {};
    for (int k0 = 0; k0 < CDIM; k0 += 32) {
        const int kq = k0 + quad * 8;
        bf16x8 ah[2], al[2], bh[8], bl[8];
        #pragma unroll
        for (int mi = 0; mi < 2; ++mi) {
            const size_t r = (size_t)(bm + mi * 16 + l16) * CDIM + kq;
            ah[mi] = *(const bf16x8*)(Xh + r);
            al[mi] = *(const bf16x8*)(Xl + r);
        }
        #pragma unroll
        for (int nf = 0; nf < 8; ++nf) {
            const size_t r = (size_t)(bn + nf * 16 + l16) * CDIM + kq;
            bh[nf] = *(const bf16x8*)(Xh + r);
            bl[nf] = *(const bf16x8*)(Xl + r);
        }
        #pragma unroll
        for (int mi = 0; mi < 2; ++mi)
            #pragma unroll
            for (int nf = 0; nf < 8; ++nf) {
                acc[mi][nf] = __builtin_amdgcn_mfma_f32_16x16x32_bf16(ah[mi], bh[nf], acc[mi][nf], 0, 0, 0);
                acc[mi][nf] = __builtin_amdgcn_mfma_f32_16x16x32_bf16(ah[mi], bl[nf], acc[mi][nf], 0, 0, 0);
                acc[mi][nf] = __builtin_amdgcn_mfma_f32_16x16x32_bf16(al[mi], bh[nf], acc[mi][nf], 0, 0, 0);
            }
    }
    #pragma unroll
    for (int mi = 0; mi < 2; ++mi)
        #pragma unroll
        for (int nf = 0; nf < 8; ++nf) {
            const int row = bm + mi * 16 + quad * 4;
            const int col = bn + nf * 16 + l16;
            #pragma unroll
            for (int r = 0; r < 4; ++r)
                Ds[(size_t)(row + r) * LDIM + ((col - row - r) & (LDIM - 1))] = acc[mi][nf][r];
        }
}

// ---------------- invn[l] = 1/max(sqrt(sum diag-neigh),eps); diag = Ds[.][0]
__global__ void k_invnorm(const float* __restrict__ Ds_, float* __restrict__ invn_,
                          size_t wsStrideB) {
    const int z = blockIdx.z;
    const float* Ds = (const float*)((const char*)Ds_ + (size_t)z * wsStrideB);
    float* invn = (float*)((char*)invn_ + (size_t)z * wsStrideB);
    const int l = blockIdx.x * 256 + threadIdx.x;
    const int ly = l >> 6, lx = l & 63;
    float s = 0.f;
    #pragma unroll
    for (int ty = -1; ty <= 1; ++ty)
        #pragma unroll
        for (int tx = -1; tx <= 1; ++tx) {
            if ((unsigned)(ly + ty) < 64u && (unsigned)(lx + tx) < 64u) {
                const int q = l + ty * Ww + tx;
                s += Ds[(size_t)q * LDIM];
            }
        }
    invn[l] = 1.0f / fmaxf(sqrtf(s), 1e-4f);
}

// ---- G[x,l] = sum_t D[x+t,l+t] read vertically from skewed Ds.
// Thread: 4 diagonals d0..d0+3 x T=8 rows; aligned float4 loads; G normal layout.
__global__ __launch_bounds__(256)
void k_gdiag(const float* __restrict__ Ds_, float* __restrict__ G_, size_t wsStrideB) {
    const int z = blockIdx.z;
    const float* Ds = (const float*)((const char*)Ds_ + (size_t)z * wsStrideB);
    float* G = (float*)((char*)G_ + (size_t)z * wsStrideB);
    constexpr int T = 8;
    const int d0 = (blockIdx.x * 256 + threadIdx.x) * 4;
    const int x0 = blockIdx.y * T;
    const int xyc = x0 >> 6;
    const int xxb = x0 & 63;
    float acc[T][4] = {};
    #pragma unroll
    for (int c = 0; c < 3; ++c) {
        const int bc = c * 64 - 65;          // -65, -1, 63
        const int ty = c - 1;
        if ((unsigned)(xyc + ty) >= 64u) continue;
        float w[T + 2][4];
        #pragma unroll
        for (int u = 0; u < T + 2; ++u) {
            const int r = x0 + bc + u;
            if ((unsigned)r < (unsigned)LDIM) {
                const f32x4 v = *(const f32x4*)(Ds + (size_t)r * LDIM + d0);
                w[u][0] = v.x; w[u][1] = v.y; w[u][2] = v.z; w[u][3] = v.w;
            } else {
                w[u][0] = w[u][1] = w[u][2] = w[u][3] = 0.f;
            }
        }
        #pragma unroll
        for (int i = 0; i < T; ++i) {
            const int px = xxb + i;
            const int p  = x0 + i;
            #pragma unroll
            for (int j = 0; j < 4; ++j) {
                const int l  = (p + d0 + j) & (LDIM - 1);
                const int ly = l >> 6, lx = l & 63;
                if ((unsigned)(ly + ty) < 64u) {
                    float s = acc[i][j];
                    if (px > 0 && lx > 0)   s += w[i][j];
                    s += w[i + 1][j];
                    if (px < 63 && lx < 63) s += w[i + 2][j];
                    acc[i][j] = s;
                }
            }
        }
    }
    #pragma unroll
    for (int i = 0; i < T; ++i) {
        const int x = x0 + i;
        const int l0i = (x + d0) & (LDIM - 1);
        float* base = G + (size_t)x * LDIM;
        if (l0i <= LDIM - 4) {
            if (!(l0i & 1)) {
                *(float2*)(base + l0i)     = make_float2(acc[i][0], acc[i][1]);
                *(float2*)(base + l0i + 2) = make_float2(acc[i][2], acc[i][3]);
            } else {
                base[l0i] = acc[i][0];
                *(float2*)(base + l0i + 1) = make_float2(acc[i][1], acc[i][2]);
                base[l0i + 3] = acc[i][3];
            }
        } else {
            #pragma unroll
            for (int j = 0; j < 4; ++j)
                base[(l0i + j) & (LDIM - 1)] = acc[i][j];
        }
    }
}

// ------- P[x,l] = (90/cnt)*invn[l]*sum_s G[x+s,l]; 4-col float4 vectorized.
// Output stored SKEWED: Ps[x][(l-x)&4095] = P[x][l]. Row softmax stats too.
__global__ __launch_bounds__(256)
void k_pool_stats(const float* __restrict__ G_, const float* __restrict__ invn_,
                  float* __restrict__ Ps_, float* __restrict__ rowm_,
                  float* __restrict__ rowrz_, size_t wsStrideB) {
    const int z = blockIdx.z;
    const float* G = (const float*)((const char*)G_ + (size_t)z * wsStrideB);
    const float* invn = (const float*)((const char*)invn_ + (size_t)z * wsStrideB);
    float* Ps = (float*)((char*)Ps_ + (size_t)z * wsStrideB);
    float* rowm = (float*)((char*)rowm_ + (size_t)z * wsStrideB);
    float* rowrz = (float*)((char*)rowrz_ + (size_t)z * wsStrideB);
    constexpr int T = 8;
    const int x0 = blockIdx.x * T;
    const int t  = threadIdx.x;
    const int xyc = x0 >> 6;
    const int xxb = x0 & 63;
    const int cy = 1 + (xyc > 0) + (xyc < 63);
    float sc[T];
    #pragma unroll
    for (int i = 0; i < T; ++i) {
        const int xx = xxb + i;
        sc[i] = 90.0f / (float)(cy * (1 + (xx > 0) + (xx < 63)));
    }
    float m[T], Z[T];
    #pragma unroll
    for (int i = 0; i < T; ++i) { m[i] = -1e30f; Z[i] = 0.f; }

    for (int ch = 0; ch < 4; ++ch) {
        const int l0 = ch * 1024 + t * 4;
        const f32x4 inl = *(const f32x4*)(invn + l0);
        f32x4 acc[T];
        #pragma unroll
        for (int i = 0; i < T; ++i) acc[i] = (f32x4){0.f, 0.f, 0.f, 0.f};
        #pragma unroll
        for (int c = 0; c < 3; ++c) {
            const int bc = c * 64 - 65;
            const int ty = c - 1;
            if ((unsigned)(xyc + ty) >= 64u) continue;
            f32x4 w[T + 2];
            #pragma unroll
            for (int u = 0; u < T + 2; ++u) {
                const int r = x0 + bc + u;
                w[u] = ((unsigned)r < (unsigned)LDIM)
                         ? *(const f32x4*)(G + (size_t)r * LDIM + l0)
                         : (f32x4){0.f, 0.f, 0.f, 0.f};
            }
            #pragma unroll
            for (int i = 0; i < T; ++i) {
                const int xx = xxb + i;
                if (xx > 0)  acc[i] += w[i];
                acc[i] += w[i + 1];
                if (xx < 63) acc[i] += w[i + 2];
            }
        }
        #pragma unroll
        for (int i = 0; i < T; ++i) {
            const f32x4 p = acc[i] * sc[i] * inl;
            const int x = x0 + i;
            const int c0 = (l0 - x) & (LDIM - 1);
            float* base = Ps + (size_t)x * LDIM;
            if (c0 <= LDIM - 4) {
                if (!(c0 & 1)) {
                    *(float2*)(base + c0)     = make_float2(p.x, p.y);
                    *(float2*)(base + c0 + 2) = make_float2(p.z, p.w);
                } else {
                    base[c0] = p.x;
                    *(float2*)(base + c0 + 1) = make_float2(p.y, p.z);
                    base[c0 + 3] = p.w;
                }
            } else {
                base[c0] = p.x;
                base[(c0 + 1) & (LDIM - 1)] = p.y;
                base[(c0 + 2) & (LDIM - 1)] = p.z;
                base[(c0 + 3) & (LDIM - 1)] = p.w;
            }
            const float mx4 = fmaxf(fmaxf(p.x, p.y), fmaxf(p.z, p.w));
            const float nm = fmaxf(m[i], mx4);
            Z[i] = Z[i] * __expf(m[i] - nm)
                 + __expf(p.x - nm) + __expf(p.y - nm)
                 + __expf(p.z - nm) + __expf(p.w - nm);
            m[i] = nm;
        }
    }
    __shared__ float sm[256], sz[256];
    for (int i = 0; i < T; ++i) {
        __syncthreads();
        sm[t] = m[i]; sz[t] = Z[i];
        __syncthreads();
        for (int off = 128; off > 0; off >>= 1) {
            if (t < off) {
                const float m2 = sm[t + off], z2 = sz[t + off];
                const float nm = fmaxf(sm[t], m2);
                sz[t] = sz[t] * __expf(sm[t] - nm) + z2 * __expf(m2 - nm);
                sm[t] = nm;
            }
            __syncthreads();
        }
        if (t == 0) { rowm[x0 + i] = sm[0]; rowrz[x0 + i] = 1.0f / sz[0]; }
    }
}

// ---- X1 [4096][128] fp32 -> X1T [128][4096] bf16 (LDS-tiled transpose)
// Launched AFTER k_pool_stats: X1T region overlaps G's tail in buf2.
__global__ __launch_bounds__(256)
void k_x1t(const float* __restrict__ X1, __hip_bfloat16* __restrict__ X1T_,
           size_t inStrideF, size_t wsStrideB) {
    const int z = blockIdx.z;
    const float* X1b = X1 + (size_t)z * inStrideF;
    __hip_bfloat16* X1T = (__hip_bfloat16*)((char*)X1T_ + (size_t)z * wsStrideB);
    __shared__ float tile[32][132];
    const int k0 = blockIdx.x * 32;
    const int t  = threadIdx.x;
    const int kr = t >> 3;
    const int c0 = (t & 7) * 16;
    #pragma unroll
    for (int j = 0; j < 4; ++j) {
        const float4 v = *(const float4*)(X1b + (size_t)(k0 + kr) * CDIM + c0 + 4 * j);
        tile[kr][c0 + 4 * j + 0] = v.x;
        tile[kr][c0 + 4 * j + 1] = v.y;
        tile[kr][c0 + 4 * j + 2] = v.z;
        tile[kr][c0 + 4 * j + 3] = v.w;
    }
    __syncthreads();
    const int c  = t >> 1;
    const int kh = (t & 1) * 16;
    __hip_bfloat16 outv[16];
    #pragma unroll
    for (int j = 0; j < 16; ++j)
        outv[j] = __float2bfloat16(tile[kh + j][c]);
    *(ushort4*)(X1T + (size_t)c * LDIM + k0 + kh)      = *(ushort4*)(outv);
    *(ushort4*)(X1T + (size_t)c * LDIM + k0 + kh + 4)  = *(ushort4*)(outv + 4);
    *(ushort4*)(X1T + (size_t)c * LDIM + k0 + kh + 8)  = *(ushort4*)(outv + 8);
    *(ushort4*)(X1T + (size_t)c * LDIM + k0 + kh + 12) = *(ushort4*)(outv + 12);
}

// ---- A2[p,q] = sum_t exp(P[p+t,q+t]-m)*rz. Reads skewed Ps vertically.
__global__ __launch_bounds__(256)
void k_att2(const float* __restrict__ Ps_, const float* __restrict__ rowm_,
            const float* __restrict__ rowrz_, __hip_bfloat16* __restrict__ A2_,
            size_t wsStrideB) {
    const int z = blockIdx.z;
    const float* Ps = (const float*)((const char*)Ps_ + (size_t)z * wsStrideB);
    const float* rowm = (const float*)((const char*)rowm_ + (size_t)z * wsStrideB);
    const float* rowrz = (const float*)((const char*)rowrz_ + (size_t)z * wsStrideB);
    __hip_bfloat16* A2 = (__hip_bfloat16*)((char*)A2_ + (size_t)z * wsStrideB);
    constexpr int T = 8;
    const int d0 = (blockIdx.x * 256 + threadIdx.x) * 4;
    const int p0 = blockIdx.y * T;
    const int pyc = p0 >> 6;
    const int pxb = p0 & 63;
    float acc[T][4] = {};
    #pragma unroll
    for (int c = 0; c < 3; ++c) {
        const int bc = c * 64 - 65;          // -65, -1, 63
        const int ty = c - 1;
        if ((unsigned)(pyc + ty) >= 64u) continue;
        float e[T + 2][4];
        #pragma unroll
        for (int u = 0; u < T + 2; ++u) {
            const int r = p0 + bc + u;
            if ((unsigned)r < (unsigned)LDIM) {
                const f32x4 w = *(const f32x4*)(Ps + (size_t)r * LDIM + d0);
                const float mr = rowm[r], rzr = rowrz[r];
                e[u][0] = __expf(w.x - mr) * rzr;
                e[u][1] = __expf(w.y - mr) * rzr;
                e[u][2] = __expf(w.z - mr) * rzr;
                e[u][3] = __expf(w.w - mr) * rzr;
            } else {
                e[u][0] = e[u][1] = e[u][2] = e[u][3] = 0.f;
            }
        }
        #pragma unroll
        for (int i = 0; i < T; ++i) {
            const int px = pxb + i;
            const int p  = p0 + i;
            #pragma unroll
            for (int j = 0; j < 4; ++j) {
                const int q  = (p + d0 + j) & (LDIM - 1);
                const int qy = q >> 6, qx = q & 63;
                if ((unsigned)(qy + ty) < 64u) {
                    float s = acc[i][j];
                    if (px > 0 && qx > 0)   s += e[i][j];
                    s += e[i + 1][j];
                    if (px < 63 && qx < 63) s += e[i + 2][j];
                    acc[i][j] = s;
                }
            }
        }
    }
    #pragma unroll
    for (int i = 0; i < T; ++i) {
        const int p = p0 + i;
        const int q0i = (p + d0) & (LDIM - 1);
        union { __hip_bfloat16 h[4]; unsigned short us[4]; unsigned int ui[2]; } cv;
        #pragma unroll
        for (int j = 0; j < 4; ++j) cv.h[j] = __float2bfloat16(acc[i][j]);
        unsigned short* bp = (unsigned short*)(A2 + (size_t)p * LDIM);
        if (q0i <= LDIM - 4) {
            if (!(q0i & 1)) {
                *(unsigned int*)(bp + q0i)     = cv.ui[0];
                *(unsigned int*)(bp + q0i + 2) = cv.ui[1];
            } else {
                bp[q0i] = cv.us[0];
                *(unsigned int*)(bp + q0i + 1) =
                    (unsigned int)cv.us[1] | ((unsigned int)cv.us[2] << 16);
                bp[q0i + 3] = cv.us[3];
            }
        } else {
            #pragma unroll
            for (int j = 0; j < 4; ++j)
                bp[(q0i + j) & (LDIM - 1)] = cv.us[j];
        }
    }
}

// ---------------- Y += A2 @ X1 (bf16 MFMA, split-K=8, atomic f32 epilogue)
__global__ __launch_bounds__(256)
void k_gemm_y(const __hip_bfloat16* __restrict__ A2b_,
              const __hip_bfloat16* __restrict__ X1T_, float* __restrict__ Y_,
              size_t wsStrideB, size_t outStrideF) {
    const int z = blockIdx.z;
    const __hip_bfloat16* A2b = (const __hip_bfloat16*)((const char*)A2b_ + (size_t)z * wsStrideB);
    const __hip_bfloat16* X1T = (const __hip_bfloat16*)((const char*)X1T_ + (size_t)z * wsStrideB);
    float* Y = Y_ + (size_t)z * outStrideF;
    const int t = threadIdx.x;
    const int wave = t >> 6, lane = t & 63;
    const int quad = lane >> 4, l16 = lane & 15;
    const int bm = blockIdx.x * 128 + wave * 32;
    const int kc = blockIdx.y * 512;
    f32x4 acc[2][8] = {};
    for (int ks = 0; ks < 512; ks += 32) {
        const int kq = kc + ks + quad * 8;
        bf16x8 a[2], b[8];
        #pragma unroll
        for (int mi = 0; mi < 2; ++mi)
            a[mi] = *(const bf16x8*)(A2b + (size_t)(bm + mi * 16 + l16) * LDIM + kq);
        #pragma unroll
        for (int nf = 0; nf < 8; ++nf)
            b[nf] = *(const bf16x8*)(X1T + (size_t)(nf * 16 + l16) * LDIM + kq);
        #pragma unroll
        for (int mi = 0; mi < 2; ++mi)
            #pragma unroll
            for (int nf = 0; nf < 8; ++nf)
                acc[mi][nf] = __builtin_amdgcn_mfma_f32_16x16x32_bf16(a[mi], b[nf], acc[mi][nf], 0, 0, 0);
    }
    #pragma unroll
    for (int mi = 0; mi < 2; ++mi)
        #pragma unroll
        for (int nf = 0; nf < 8; ++nf)
            #pragma unroll
            for (int r = 0; r < 4; ++r)
                atomicAdd(Y + (size_t)(bm + mi * 16 + quad * 4 + r) * CDIM + nf * 16 + l16,
                          acc[mi][nf][r]);
}

extern "C" void kernel_launch(void* const* d_in, const int* in_sizes, int n_in,
                              void* d_out, int out_size, void* d_ws, size_t ws_size,
                              hipStream_t stream) {
    const float* x1 = (const float*)d_in[0];
    const float* x2 = (const float*)d_in[1];
    float* out = (float*)d_out;

    const size_t MATB = (size_t)LDIM * LDIM * sizeof(float);   // 64 MB
    // per-batch slice: buf1 (64MB) + buf2 (64MB) + invn/rowm/rowrz (48KB, padded)
    const size_t SMALLB = (size_t)64 * 1024;
    const size_t SLICE = 2 * MATB + SMALLB;

    const int B = in_sizes[0] / (LDIM * CDIM);
    const size_t inStrideF = (size_t)LDIM * CDIM;
    const bool concurrent = ((size_t)B * SLICE <= ws_size);

    hipMemsetAsync(d_out, 0, (size_t)out_size * sizeof(float), stream);

    const int NB = concurrent ? B : 1;         // grid.z
    const int NL = concurrent ? 1 : B;         // host loop count
    const size_t wsStrideB = concurrent ? SLICE : 0;

    for (int b = 0; b < NL; ++b) {
        char* ws = (char*)d_ws + (concurrent ? 0 : (size_t)0);  // slice 0 reused in seq mode
        float* buf1  = (float*)ws;                         // Ds, then Ps (fp32)
        char*  buf2c = ws + MATB;                          // multi-use 64 MB
        float* buf2  = (float*)buf2c;                      // G (fp32)
        __hip_bfloat16* X2h = (__hip_bfloat16*)buf2c;                    // 1 MB
        __hip_bfloat16* X2l = (__hip_bfloat16*)(buf2c + (size_t)LDIM * CDIM * 2);
        __hip_bfloat16* A2b = (__hip_bfloat16*)buf2c;                    // 32 MB
        __hip_bfloat16* X1T = (__hip_bfloat16*)(buf2c + MATB / 2);       // 1 MB
        float* invn  = (float*)(ws + 2 * MATB);
        float* rowm  = invn + LDIM;
        float* rowrz = rowm + LDIM;

        const float* X2b_ = x2 + (size_t)b * inStrideF;
        const float* X1b_ = x1 + (size_t)b * inStrideF;
        float* Yb = out + (size_t)b * inStrideF;
        const size_t inS = concurrent ? inStrideF : 0;
        const size_t outS = concurrent ? inStrideF : 0;

        k_split     <<<dim3(LDIM * CDIM / 1024, 1, NB), 256, 0, stream>>>(X2b_, X2h, X2l, inS, wsStrideB);
        k_gemm_d    <<<dim3(LDIM / 128, LDIM / 128, NB), 256, 0, stream>>>(X2h, X2l, buf1, wsStrideB);
        k_invnorm   <<<dim3(LDIM / 256, 1, NB), 256, 0, stream>>>(buf1, invn, wsStrideB);
        k_gdiag     <<<dim3(LDIM / 1024, LDIM / 8, NB), 256, 0, stream>>>(buf1, buf2, wsStrideB);
        k_pool_stats<<<dim3(LDIM / 8, 1, NB), 256, 0, stream>>>(buf2, invn, buf1, rowm, rowrz, wsStrideB);
        k_x1t       <<<dim3(LDIM / 32, 1, NB), 256, 0, stream>>>(X1b_, X1T, inS, wsStrideB);
        k_att2      <<<dim3(LDIM / 1024, LDIM / 8, NB), 256, 0, stream>>>(buf1, rowm, rowrz, A2b, wsStrideB);
        k_gemm_y    <<<dim3(LDIM / 128, 8, NB), 256, 0, stream>>>(A2b, X1T, Yb, wsStrideB, outS);
    }
}